// Round 1
// baseline (1728.772 us; speedup 1.0000x reference)
//
#include <hip/hip_runtime.h>
#include <math.h>

#define NPTS 524288

// ---- glob layer segment: 4 output rows, 19 inputs from SRC at weight offset OFF ----
#define GLOB_SEG(SRC, OFF)                                    \
    _Pragma("unroll")                                         \
    for (int k = 0; k < 19; ++k) {                            \
        const float xv = (SRC)[k];                            \
        a0 = fmaf(xv, w0[(OFF) + k],       a0);               \
        a1 = fmaf(xv, w0[57 + (OFF) + k],  a1);               \
        a2 = fmaf(xv, w0[114 + (OFF) + k], a2);               \
        a3 = fmaf(xv, w0[171 + (OFF) + k], a3);               \
    }

// ---- col1 layer segment: 4 output rows, CNT inputs from SRC at weight offset OFF ----
#define COL1_SEG(SRC, OFF, CNT)                               \
    _Pragma("unroll")                                         \
    for (int k = 0; k < (CNT); ++k) {                         \
        const float xv = (SRC)[k];                            \
        a0 = fmaf(xv, w0[(OFF) + k],        a0);              \
        a1 = fmaf(xv, w0[111 + (OFF) + k],  a1);              \
        a2 = fmaf(xv, w0[222 + (OFF) + k],  a2);              \
        a3 = fmaf(xv, w0[333 + (OFF) + k],  a3);              \
    }

__global__ __launch_bounds__(256) void nerf_fused(
    const float* __restrict__ vox,      // [N,8]
    const float* __restrict__ img,      // [N,4,23]
    const float* __restrict__ view_w, const float* __restrict__ view_b,   // [19,4],[19]
    const float* __restrict__ glob_w, const float* __restrict__ glob_b,   // [32,57],[32]
    const float* __restrict__ aggw_w, const float* __restrict__ aggw_b,   // [1,32],[1]
    const float* __restrict__ fc_w,   const float* __restrict__ fc_b,     // [16,32],[16]
    const float* __restrict__ lr0_w,  const float* __restrict__ lr0_b,    // [64,24],[64]
    const float* __restrict__ sgm_w,  const float* __restrict__ sgm_b,    // [1,64],[1]
    const float* __restrict__ col1_w, const float* __restrict__ col1_b,   // [64,111],[64]
    const float* __restrict__ col2_w, const float* __restrict__ col2_b,   // [1,64],[1]
    float* __restrict__ out)            // [N,4]
{
    // private per-thread LDS stripe, only used to round-trip values written at
    // dynamic (loop-variable) indices back to constant-indexed registers.
    // layout [slot][tid]: lane i -> bank i%32, 2 lanes/bank (free on gfx950).
    __shared__ float sbuf[32 * 256];
    const int tid = threadIdx.x;
    const int n = blockIdx.x * 256 + tid;

    // ---------------- phase 1: load point, view head, residual ----------------
    float raw[92];
    {
        const float4* p4 = reinterpret_cast<const float4*>(img) + (size_t)n * 23;
        #pragma unroll
        for (int i = 0; i < 23; ++i) {
            float4 v = p4[i];
            raw[4*i+0] = v.x; raw[4*i+1] = v.y; raw[4*i+2] = v.z; raw[4*i+3] = v.w;
        }
    }

    float ifr[4][19];   // img_feat_rgb = raw[:19] + relu(view(dir))
    #pragma unroll
    for (int s = 0; s < 4; ++s) {
        const float d0 = raw[23*s+19], d1 = raw[23*s+20];
        const float d2 = raw[23*s+21], d3 = raw[23*s+22];
        #pragma unroll
        for (int c = 0; c < 19; ++c) {
            float vf = view_b[c];
            vf = fmaf(d0, view_w[4*c+0], vf);
            vf = fmaf(d1, view_w[4*c+1], vf);
            vf = fmaf(d2, view_w[4*c+2], vf);
            vf = fmaf(d3, view_w[4*c+3], vf);
            ifr[s][c] = raw[23*s+c] + fmaxf(vf, 0.f);
        }
    }

    // ---------------- mean / unbiased var over samples ----------------
    float mean[19], var[19];
    #pragma unroll
    for (int c = 0; c < 19; ++c) {
        float m = (ifr[0][c] + ifr[1][c] + ifr[2][c] + ifr[3][c]) * 0.25f;
        float v = 0.f;
        #pragma unroll
        for (int s = 0; s < 4; ++s) { float d = ifr[s][c] - m; v = fmaf(d, d, v); }
        mean[c] = m; var[c] = v * (1.f / 3.f);
    }

    // ---------------- glob layer + online-softmax aggregation ----------------
    float vec[32];                       // running weighted sum of global_feat
    #pragma unroll
    for (int c = 0; c < 32; ++c) vec[c] = 0.f;
    float msm = -3.0e38f, dsm = 0.f;

    #pragma unroll
    for (int s = 0; s < 4; ++s) {
        #pragma unroll 1
        for (int o = 0; o < 32; o += 4) {
            float a0 = glob_b[o], a1 = glob_b[o+1], a2 = glob_b[o+2], a3 = glob_b[o+3];
            const float* w0 = glob_w + o * 57;
            GLOB_SEG(ifr[s], 0)
            GLOB_SEG(var,   19)
            GLOB_SEG(mean,  38)
            sbuf[(o+0)*256 + tid] = fmaxf(a0, 0.f);
            sbuf[(o+1)*256 + tid] = fmaxf(a1, 0.f);
            sbuf[(o+2)*256 + tid] = fmaxf(a2, 0.f);
            sbuf[(o+3)*256 + tid] = fmaxf(a3, 0.f);
        }
        float z = aggw_b[0];
        #pragma unroll
        for (int c = 0; c < 32; ++c) z = fmaf(sbuf[c*256 + tid], aggw_w[c], z);
        z = fmaxf(z, 0.f);
        const float mnew = fmaxf(msm, z);
        const float corr = expf(msm - mnew);   // first iter: exp(-inf) -> 0
        const float beta = expf(z - mnew);
        dsm = fmaf(dsm, corr, beta);
        #pragma unroll
        for (int c = 0; c < 32; ++c)
            vec[c] = fmaf(vec[c], corr, sbuf[c*256 + tid] * beta);
        msm = mnew;
    }
    {
        const float inv_d = 1.f / dsm;
        #pragma unroll
        for (int c = 0; c < 32; ++c) vec[c] *= inv_d;   // vec = im_feat
    }

    // ---------------- fc -> img_feat, concat with vox -> vif[24] ----------------
    float vif[24];
    {
        const float4* v4 = reinterpret_cast<const float4*>(vox) + (size_t)n * 2;
        float4 a = v4[0], b = v4[1];
        vif[0]=a.x; vif[1]=a.y; vif[2]=a.z; vif[3]=a.w;
        vif[4]=b.x; vif[5]=b.y; vif[6]=b.z; vif[7]=b.w;
    }
    #pragma unroll
    for (int o = 0; o < 16; ++o) {
        float a = fc_b[o];
        #pragma unroll
        for (int k = 0; k < 32; ++k) a = fmaf(vec[k], fc_w[o*32 + k], a);
        vif[8 + o] = fmaxf(a, 0.f);
    }

    // ---------------- lr0 -> x[64] (via LDS stripe, two halves) ----------------
    float x[64];
    #pragma unroll 1
    for (int o = 0; o < 32; o += 4) {
        float a0 = lr0_b[o], a1 = lr0_b[o+1], a2 = lr0_b[o+2], a3 = lr0_b[o+3];
        const float* w0 = lr0_w + o * 24;
        #pragma unroll
        for (int k = 0; k < 24; ++k) {
            const float xv = vif[k];
            a0 = fmaf(xv, w0[k],      a0);
            a1 = fmaf(xv, w0[24 + k], a1);
            a2 = fmaf(xv, w0[48 + k], a2);
            a3 = fmaf(xv, w0[72 + k], a3);
        }
        sbuf[(o+0)*256 + tid] = fmaxf(a0, 0.f);
        sbuf[(o+1)*256 + tid] = fmaxf(a1, 0.f);
        sbuf[(o+2)*256 + tid] = fmaxf(a2, 0.f);
        sbuf[(o+3)*256 + tid] = fmaxf(a3, 0.f);
    }
    #pragma unroll
    for (int k = 0; k < 32; ++k) x[k] = sbuf[k*256 + tid];
    #pragma unroll 1
    for (int o = 32; o < 64; o += 4) {
        float a0 = lr0_b[o], a1 = lr0_b[o+1], a2 = lr0_b[o+2], a3 = lr0_b[o+3];
        const float* w0 = lr0_w + o * 24;
        #pragma unroll
        for (int k = 0; k < 24; ++k) {
            const float xv = vif[k];
            a0 = fmaf(xv, w0[k],      a0);
            a1 = fmaf(xv, w0[24 + k], a1);
            a2 = fmaf(xv, w0[48 + k], a2);
            a3 = fmaf(xv, w0[72 + k], a3);
        }
        sbuf[(o-32+0)*256 + tid] = fmaxf(a0, 0.f);
        sbuf[(o-32+1)*256 + tid] = fmaxf(a1, 0.f);
        sbuf[(o-32+2)*256 + tid] = fmaxf(a2, 0.f);
        sbuf[(o-32+3)*256 + tid] = fmaxf(a3, 0.f);
    }
    #pragma unroll
    for (int k = 0; k < 32; ++k) x[32 + k] = sbuf[k*256 + tid];

    // ---------------- sigma = softplus(sigma_w . x) ----------------
    float zs = sgm_b[0];
    #pragma unroll
    for (int k = 0; k < 64; ++k) zs = fmaf(x[k], sgm_w[k], zs);
    const float sigma = fmaxf(zs, 0.f) + log1pf(expf(-fabsf(zs)));

    // ---------------- col1/col2 per sample + online-softmax color ----------------
    float c0 = 0.f, c1 = 0.f, c2 = 0.f, m2 = -3.0e38f, d2 = 0.f;
    const float* imgp = img + (size_t)n * 92;
    #pragma unroll 1
    for (int s = 0; s < 4; ++s) {
        float rs[23];
        #pragma unroll
        for (int c = 0; c < 23; ++c) rs[c] = imgp[23*s + c];
        float z = col2_b[0];
        #pragma unroll 1
        for (int o = 0; o < 64; o += 4) {
            float a0 = col1_b[o], a1 = col1_b[o+1], a2 = col1_b[o+2], a3 = col1_b[o+3];
            const float* w0 = col1_w + o * 111;
            COL1_SEG(x,   0, 64)
            COL1_SEG(vif, 64, 24)
            COL1_SEG(rs,  88, 23)
            z = fmaf(fmaxf(a0, 0.f), col2_w[o+0], z);
            z = fmaf(fmaxf(a1, 0.f), col2_w[o+1], z);
            z = fmaf(fmaxf(a2, 0.f), col2_w[o+2], z);
            z = fmaf(fmaxf(a3, 0.f), col2_w[o+3], z);
        }
        z = fmaxf(z, 0.f);
        const float mnew = fmaxf(m2, z);
        const float corr = expf(m2 - mnew);
        const float beta = expf(z - mnew);
        d2 = fmaf(d2, corr, beta);
        c0 = fmaf(c0, corr, rs[16] * beta);
        c1 = fmaf(c1, corr, rs[17] * beta);
        c2 = fmaf(c2, corr, rs[18] * beta);
        m2 = mnew;
    }
    const float invd2 = 1.f / d2;
    reinterpret_cast<float4*>(out)[n] =
        make_float4(c0 * invd2, c1 * invd2, c2 * invd2, sigma);
}

extern "C" void kernel_launch(void* const* d_in, const int* in_sizes, int n_in,
                              void* d_out, int out_size, void* d_ws, size_t ws_size,
                              hipStream_t stream) {
    (void)in_sizes; (void)n_in; (void)out_size; (void)d_ws; (void)ws_size;
    const float* vox    = (const float*)d_in[0];
    const float* img    = (const float*)d_in[1];
    const float* view_w = (const float*)d_in[2];
    const float* view_b = (const float*)d_in[3];
    const float* glob_w = (const float*)d_in[4];
    const float* glob_b = (const float*)d_in[5];
    const float* aggw_w = (const float*)d_in[6];
    const float* aggw_b = (const float*)d_in[7];
    const float* fc_w   = (const float*)d_in[8];
    const float* fc_b   = (const float*)d_in[9];
    const float* lr0_w  = (const float*)d_in[10];
    const float* lr0_b  = (const float*)d_in[11];
    const float* sgm_w  = (const float*)d_in[12];
    const float* sgm_b  = (const float*)d_in[13];
    const float* col1_w = (const float*)d_in[14];
    const float* col1_b = (const float*)d_in[15];
    const float* col2_w = (const float*)d_in[16];
    const float* col2_b = (const float*)d_in[17];
    float* out = (float*)d_out;

    nerf_fused<<<dim3(NPTS / 256), dim3(256), 0, stream>>>(
        vox, img, view_w, view_b, glob_w, glob_b, aggw_w, aggw_b,
        fc_w, fc_b, lr0_w, lr0_b, sgm_w, sgm_b, col1_w, col1_b,
        col2_w, col2_b, out);
}

// Round 2
// 595.371 us; speedup vs baseline: 2.9037x; 2.9037x over previous
//
#include <hip/hip_runtime.h>
#include <math.h>

#define NPTS   524288
#define GROUPS 4          // 16 pts/wave/group * 4 waves * 4 groups = 256 pts/block

typedef __attribute__((ext_vector_type(8))) short  short8;
typedef __attribute__((ext_vector_type(4))) float  f32x4;
typedef __attribute__((ext_vector_type(4))) int    int4v;

#define MFMA16(a, b, c) __builtin_amdgcn_mfma_f32_16x16x32_bf16((a), (b), (c), 0, 0, 0)

// f32 -> bf16 bits, round-half-up (max err ~0.5 ulp_bf16)
__device__ __forceinline__ unsigned bfbits(float x) {
    union { float f; unsigned u; } a; a.f = x;
    return (a.u + 0x8000u) >> 16;
}
// pack two f32 into one dword of two bf16 (lo, hi)
__device__ __forceinline__ int pk2(float lo, float hi) {
    union { float f; unsigned u; } a, b; a.f = lo; b.f = hi;
    return (int)(((a.u + 0x8000u) >> 16) | ((b.u + 0x8000u) & 0xFFFF0000u));
}

// B-fragment loader: B[n][k = kbase + q*8 + j] from row-major W[n][ld], zero past klim
__device__ __forceinline__ short8 ldfrag(const float* __restrict__ W, int n, int ld,
                                         int klim, int kbase, int q) {
    short8 r;
    #pragma unroll
    for (int j = 0; j < 8; ++j) {
        int k = kbase + q * 8 + j;
        float v = (k < klim) ? W[n * ld + k] : 0.f;
        r[j] = (short)bfbits(v);
    }
    return r;
}

__device__ __forceinline__ f32x4 relub(f32x4 v, float b) {
    f32x4 r;
    #pragma unroll
    for (int i = 0; i < 4; ++i) r[i] = fmaxf(v[i] + b, 0.f);
    return r;
}

// sum across the 16 lanes of a quad (xor 1,2,4,8), per component
__device__ __forceinline__ f32x4 bfly16(f32x4 v) {
    #pragma unroll
    for (int d = 1; d <= 8; d <<= 1) {
        #pragma unroll
        for (int i = 0; i < 4; ++i) v[i] += __shfl_xor(v[i], d, 64);
    }
    return v;
}

// per-component softmax over 4 vectors (in place -> weights)
__device__ __forceinline__ void softmax4(f32x4& a, f32x4& b, f32x4& c, f32x4& d) {
    #pragma unroll
    for (int i = 0; i < 4; ++i) {
        float m  = fmaxf(fmaxf(a[i], b[i]), fmaxf(c[i], d[i]));
        float e0 = __expf(a[i] - m), e1 = __expf(b[i] - m);
        float e2 = __expf(c[i] - m), e3 = __expf(d[i] - m);
        float inv = 1.f / (e0 + e1 + e2 + e3);
        a[i] = e0 * inv; b[i] = e1 * inv; c[i] = e2 * inv; d[i] = e3 * inv;
    }
}

// dynamic component extract without scratch (cndmask tree)
__device__ __forceinline__ float sel4(f32x4 v, int r) {
    float a = (r & 1) ? v[1] : v[0];
    float b = (r & 1) ? v[3] : v[2];
    return (r & 2) ? b : a;
}

// per-wave LDS region offsets (bytes); FEATA is unioned with XA+FCA (disjoint lifetimes)
#define FEATA 0        // 4s x 8c x 16row x 16B = 8192
#define XA    0        // 8c x 16row x 16B = 2048   (x activations, written stage12)
#define FCA   2048     // 4c x 16row x 16B = 1024   (im_feat,     written stage7)
#define VIFA  8192     // 4c x 16row x 16B = 1024   (c0=vox, c1/c2=fc out, c3=zeros)
#define RS    9216     // 3c x 64row x 16B = 3072   (raw img rows, bf16)
#define RSZ   12288    // 16B zeros
#define RGB   12304    // 64row x 16B = 1024        (rgb fp32)
#define WLDS  13328

__global__ __launch_bounds__(256) void nerf_mfma(
    const float* __restrict__ vox, const float* __restrict__ img,
    const float* __restrict__ view_w, const float* __restrict__ view_b,
    const float* __restrict__ glob_w, const float* __restrict__ glob_b,
    const float* __restrict__ aggw_w, const float* __restrict__ aggw_b,
    const float* __restrict__ fc_w,   const float* __restrict__ fc_b,
    const float* __restrict__ lr0_w,  const float* __restrict__ lr0_b,
    const float* __restrict__ sgm_w,  const float* __restrict__ sgm_b,
    const float* __restrict__ col1_w, const float* __restrict__ col1_b,
    const float* __restrict__ col2_w, const float* __restrict__ col2_b,
    float* __restrict__ out)
{
    __shared__ int4v smem[(4 * WLDS) / 16];
    const int tid  = threadIdx.x;
    const int wv   = tid >> 6;
    const int lane = tid & 63;
    const int lp   = lane & 15;   // A-row point / C-column
    const int q    = lane >> 4;   // quad (= sample index in row-stages)
    char* S = (char*)smem + wv * WLDS;

    // ---- one-time zero pads ----
    int4v zeroi = {0, 0, 0, 0};
    if (q == 3) {
        *(int4v*)(S + VIFA + (3 * 16 + lp) * 16) = zeroi;   // vif pad chunk (k=24..31)
        if (lp == 0) *(int4v*)(S + RSZ) = zeroi;            // col1 k=112..127 pad
    }

    // ---- one-time B-fragments (weights live in VGPRs for the whole kernel) ----
    short8 bg[2][2], blr[4], bc[4][4], bfc;
    #pragma unroll
    for (int nt = 0; nt < 2; ++nt)
        #pragma unroll
        for (int ks = 0; ks < 2; ++ks)
            bg[nt][ks] = ldfrag(glob_w, nt * 16 + lp, 57, 57, ks * 32, q);
    bfc = ldfrag(fc_w, lp, 32, 32, 0, q);
    #pragma unroll
    for (int nt = 0; nt < 4; ++nt) blr[nt] = ldfrag(lr0_w, nt * 16 + lp, 24, 24, 0, q);
    #pragma unroll
    for (int nt = 0; nt < 4; ++nt)
        #pragma unroll
        for (int ks = 0; ks < 4; ++ks)
            bc[nt][ks] = ldfrag(col1_w, nt * 16 + lp, 111, 111, ks * 32, q);

    // ---- per-lane (column-indexed) biases/row-vectors ----
    const float gb0 = glob_b[lp], gb1 = glob_b[16 + lp];
    const float aw0 = aggw_w[lp], aw1 = aggw_w[16 + lp];
    const float fcb = fc_b[lp];
    float lb[4], sw[4], c1b[4], c2w[4];
    #pragma unroll
    for (int nt = 0; nt < 4; ++nt) {
        lb[nt]  = lr0_b[nt * 16 + lp];
        sw[nt]  = sgm_w[nt * 16 + lp];
        c1b[nt] = col1_b[nt * 16 + lp];
        c2w[nt] = col2_w[nt * 16 + lp];
    }
    const float ab0 = aggw_b[0], sb0 = sgm_b[0], c2b0 = col2_b[0];

    #pragma unroll 1
    for (int g = 0; g < GROUPS; ++g) {
        const int n0 = blockIdx.x * (64 * GROUPS) + g * 64 + wv * 16;

        // ---------- stage 1: load row (point lp, sample q); stash rs/rgb/vox ----------
        float raw[23];
        {
            const float* rp = img + ((size_t)(n0 + lp) * 4 + q) * 23;
            #pragma unroll
            for (int i = 0; i < 23; ++i) raw[i] = rp[i];
            int4v w0v = { pk2(raw[0], raw[1]),  pk2(raw[2], raw[3]),
                          pk2(raw[4], raw[5]),  pk2(raw[6], raw[7]) };
            *(int4v*)(S + RS + (q * 16 + lp) * 16) = w0v;
            int4v w1v = { pk2(raw[8], raw[9]),  pk2(raw[10], raw[11]),
                          pk2(raw[12], raw[13]), pk2(raw[14], raw[15]) };
            *(int4v*)(S + RS + (64 + q * 16 + lp) * 16) = w1v;
            int4v w2v = { pk2(raw[16], raw[17]), pk2(raw[18], raw[19]),
                          pk2(raw[20], raw[21]), pk2(raw[22], 0.f) };
            *(int4v*)(S + RS + (128 + q * 16 + lp) * 16) = w2v;
            f32x4 rgbv = { raw[16], raw[17], raw[18], 0.f };
            *(f32x4*)(S + RGB + (q * 16 + lp) * 16) = rgbv;
            if (q == 0) {   // vox -> vif chunk 0
                const float* vp = vox + (size_t)(n0 + lp) * 8;
                f32x4 v0 = *(const f32x4*)vp;
                f32x4 v1 = *(const f32x4*)(vp + 4);
                int4v c8 = { pk2(v0[0], v0[1]), pk2(v0[2], v0[3]),
                             pk2(v1[0], v1[1]), pk2(v1[2], v1[3]) };
                *(int4v*)(S + VIFA + lp * 16) = c8;
            }
        }

        // ---------- stage 2+3: view head, mean/var over samples (shfl over q-bits) ----------
        float feat[64];
        {
            const float d0 = raw[19], d1 = raw[20], d2 = raw[21], d3 = raw[22];
            #pragma unroll
            for (int c = 0; c < 19; ++c) {
                float vf = view_b[c];
                vf = fmaf(d0, view_w[4 * c + 0], vf);
                vf = fmaf(d1, view_w[4 * c + 1], vf);
                vf = fmaf(d2, view_w[4 * c + 2], vf);
                vf = fmaf(d3, view_w[4 * c + 3], vf);
                float v  = raw[c] + fmaxf(vf, 0.f);
                float t  = v + __shfl_xor(v, 16, 64);
                float s4 = t + __shfl_xor(t, 32, 64);
                float m  = s4 * 0.25f;
                float dd = v - m;
                float ds = dd * dd;
                float t2 = ds + __shfl_xor(ds, 16, 64);
                float sq = t2 + __shfl_xor(t2, 32, 64);
                feat[c]      = v;
                feat[19 + c] = sq * (1.f / 3.f);   // unbiased var (ddof=1)
                feat[38 + c] = m;
            }
            #pragma unroll
            for (int c = 57; c < 64; ++c) feat[c] = 0.f;
        }

        // ---------- stage 4: write glob A-fragments ----------
        #pragma unroll
        for (int c = 0; c < 8; ++c) {
            int4v wv4 = { pk2(feat[8 * c + 0], feat[8 * c + 1]), pk2(feat[8 * c + 2], feat[8 * c + 3]),
                          pk2(feat[8 * c + 4], feat[8 * c + 5]), pk2(feat[8 * c + 6], feat[8 * c + 7]) };
            *(int4v*)(S + FEATA + ((q * 8 + c) * 16 + lp) * 16) = wv4;
        }
        __syncthreads();

        // ---------- stage 5: glob GEMM (rows=(pt,s), cols=32, K=64) ----------
        f32x4 ag[4][2] = {};
        #pragma unroll
        for (int s = 0; s < 4; ++s)
            #pragma unroll
            for (int ks = 0; ks < 2; ++ks) {
                int4v av = *(int4v*)(S + FEATA + ((s * 8 + ks * 4 + q) * 16 + lp) * 16);
                short8 a = __builtin_bit_cast(short8, av);
                ag[s][0] = MFMA16(a, bg[0][ks], ag[s][0]);
                ag[s][1] = MFMA16(a, bg[1][ks], ag[s][1]);
            }

        // ---------- stage 6: relu+agg softmax -> im_feat (C-layout lanes) ----------
        f32x4 gg[4][2], wsm[4];
        #pragma unroll
        for (int s = 0; s < 4; ++s) {
            gg[s][0] = relub(ag[s][0], gb0);
            gg[s][1] = relub(ag[s][1], gb1);
            f32x4 zp = gg[s][0] * aw0 + gg[s][1] * aw1;
            zp = bfly16(zp);
            wsm[s] = relub(zp, ab0);
        }
        softmax4(wsm[0], wsm[1], wsm[2], wsm[3]);
        f32x4 im0 = {}, im1 = {};
        #pragma unroll
        for (int s = 0; s < 4; ++s) { im0 += gg[s][0] * wsm[s]; im1 += gg[s][1] * wsm[s]; }

        // ---------- stage 7: scatter im_feat to fc A-fragments (bf16) ----------
        {
            short* fca = (short*)(S + FCA);
            #pragma unroll
            for (int r = 0; r < 4; ++r) {
                fca[((lp >> 3)) * 128     + (q * 4 + r) * 8 + (lp & 7)] = (short)bfbits(im0[r]);
                fca[(2 + (lp >> 3)) * 128 + (q * 4 + r) * 8 + (lp & 7)] = (short)bfbits(im1[r]);
            }
        }
        __syncthreads();

        // ---------- stage 8: fc GEMM (rows=pts, cols=16, K=32) ----------
        f32x4 fco;
        {
            int4v av = *(int4v*)(S + FCA + (q * 16 + lp) * 16);
            f32x4 acc = {};
            acc = MFMA16(__builtin_bit_cast(short8, av), bfc, acc);
            fco = relub(acc, fcb);
        }

        // ---------- stage 9: fc out -> vif chunks 1,2 ----------
        {
            short* vfa = (short*)(S + VIFA);
            #pragma unroll
            for (int r = 0; r < 4; ++r)
                vfa[(1 + (lp >> 3)) * 128 + (q * 4 + r) * 8 + (lp & 7)] = (short)bfbits(fco[r]);
        }
        __syncthreads();

        // ---------- stage 10: lr0 GEMM (rows=pts, cols=64, K=32) ----------
        f32x4 x4[4];
        {
            int4v av = *(int4v*)(S + VIFA + (q * 16 + lp) * 16);
            short8 a = __builtin_bit_cast(short8, av);
            #pragma unroll
            for (int nt = 0; nt < 4; ++nt) {
                f32x4 acc = {};
                acc = MFMA16(a, blr[nt], acc);
                x4[nt] = relub(acc, lb[nt]);
            }
        }

        // ---------- stage 11: sigma = softplus(sgm_w . x) ----------
        f32x4 sig;
        {
            f32x4 sp = x4[0] * sw[0] + x4[1] * sw[1] + x4[2] * sw[2] + x4[3] * sw[3];
            sp = bfly16(sp);
            #pragma unroll
            for (int i = 0; i < 4; ++i) {
                float z = sp[i] + sb0;
                sig[i] = fmaxf(z, 0.f) + log1pf(__expf(-fabsf(z)));
            }
        }

        // ---------- stage 12: x -> col1 A-fragments (chunks 0..7) ----------
        {
            short* xa = (short*)(S + XA);
            #pragma unroll
            for (int nt = 0; nt < 4; ++nt)
                #pragma unroll
                for (int r = 0; r < 4; ++r)
                    xa[(nt * 2 + (lp >> 3)) * 128 + (q * 4 + r) * 8 + (lp & 7)] =
                        (short)bfbits(x4[nt][r]);
        }
        __syncthreads();

        // ---------- stage 13: col1 GEMM (rows=(pt,s), cols=64, K=128) ----------
        f32x4 ac[4][4] = {};
        {
            short8 ax0 = __builtin_bit_cast(short8, *(int4v*)(S + XA + (q * 16 + lp) * 16));
            short8 ax1 = __builtin_bit_cast(short8, *(int4v*)(S + XA + ((4 + q) * 16 + lp) * 16));
            #pragma unroll
            for (int mt = 0; mt < 4; ++mt) {
                const char* a2p = (q < 3) ? (S + VIFA + (q * 16 + lp) * 16)
                                          : (S + RS + (mt * 16 + lp) * 16);
                const char* a3p = (q == 0) ? (S + RS + (64 + mt * 16 + lp) * 16)
                                : (q == 1) ? (S + RS + (128 + mt * 16 + lp) * 16)
                                           : (S + RSZ);
                short8 a2 = __builtin_bit_cast(short8, *(const int4v*)a2p);
                short8 a3 = __builtin_bit_cast(short8, *(const int4v*)a3p);
                #pragma unroll
                for (int nt = 0; nt < 4; ++nt) {
                    ac[mt][nt] = MFMA16(ax0, bc[nt][0], ac[mt][nt]);
                    ac[mt][nt] = MFMA16(ax1, bc[nt][1], ac[mt][nt]);
                    ac[mt][nt] = MFMA16(a2,  bc[nt][2], ac[mt][nt]);
                    ac[mt][nt] = MFMA16(a3,  bc[nt][3], ac[mt][nt]);
                }
            }
        }

        // ---------- stage 14: col2, softmax over s, color + store ----------
        f32x4 z2[4];
        #pragma unroll
        for (int s = 0; s < 4; ++s) {
            f32x4 zp = {};
            #pragma unroll
            for (int nt = 0; nt < 4; ++nt) {
                f32x4 h = relub(ac[s][nt], c1b[nt]);
                zp += h * c2w[nt];
            }
            zp = bfly16(zp);
            z2[s] = relub(zp, c2b0);
        }
        softmax4(z2[0], z2[1], z2[2], z2[3]);
        if (lp < 4) {
            float cr = 0.f, cg = 0.f, cb = 0.f;
            #pragma unroll
            for (int s = 0; s < 4; ++s) {
                f32x4 rgbv = *(f32x4*)(S + RGB + (s * 16 + q * 4 + lp) * 16);
                float ws = sel4(z2[s], lp);
                cr = fmaf(rgbv[0], ws, cr);
                cg = fmaf(rgbv[1], ws, cg);
                cb = fmaf(rgbv[2], ws, cb);
            }
            f32x4 o = { cr, cg, cb, sel4(sig, lp) };
            *(f32x4*)(out + (size_t)(n0 + q * 4 + lp) * 4) = o;
        }
        __syncthreads();
    }
}

extern "C" void kernel_launch(void* const* d_in, const int* in_sizes, int n_in,
                              void* d_out, int out_size, void* d_ws, size_t ws_size,
                              hipStream_t stream) {
    (void)in_sizes; (void)n_in; (void)out_size; (void)d_ws; (void)ws_size;
    nerf_mfma<<<dim3(NPTS / (64 * GROUPS)), dim3(256), 0, stream>>>(
        (const float*)d_in[0],  (const float*)d_in[1],
        (const float*)d_in[2],  (const float*)d_in[3],
        (const float*)d_in[4],  (const float*)d_in[5],
        (const float*)d_in[6],  (const float*)d_in[7],
        (const float*)d_in[8],  (const float*)d_in[9],
        (const float*)d_in[10], (const float*)d_in[11],
        (const float*)d_in[12], (const float*)d_in[13],
        (const float*)d_in[14], (const float*)d_in[15],
        (const float*)d_in[16], (const float*)d_in[17],
        (float*)d_out);
}

// Round 3
// 571.564 us; speedup vs baseline: 3.0246x; 1.0417x over previous
//
#include <hip/hip_runtime.h>
#include <math.h>

#define NPTS   524288
#define GROUPS 4          // 16 pts/wave/group * 4 waves * 4 groups = 256 pts/block

typedef __attribute__((ext_vector_type(8))) short  short8;
typedef __attribute__((ext_vector_type(4))) float  f32x4;
typedef __attribute__((ext_vector_type(4))) int    int4v;

#define MFMA16(a, b, c) __builtin_amdgcn_mfma_f32_16x16x32_bf16((a), (b), (c), 0, 0, 0)

// wave-private LDS ordering: compile-time fence only (LDS executes in wave
// program order; block barrier not needed since LDS stripes are per-wave)
#define WFENCE() __builtin_amdgcn_wave_barrier()

// f32 -> bf16 bits, round-half-up (max err ~0.5 ulp_bf16)
__device__ __forceinline__ unsigned bfbits(float x) {
    union { float f; unsigned u; } a; a.f = x;
    return (a.u + 0x8000u) >> 16;
}
// pack two f32 into one dword of two bf16 (lo, hi)
__device__ __forceinline__ int pk2(float lo, float hi) {
    union { float f; unsigned u; } a, b; a.f = lo; b.f = hi;
    return (int)(((a.u + 0x8000u) >> 16) | ((b.u + 0x8000u) & 0xFFFF0000u));
}

// B-fragment loader: B[n][k = kbase + q*8 + j] from row-major W[n][ld], zero past klim
__device__ __forceinline__ short8 ldfrag(const float* __restrict__ W, int n, int ld,
                                         int klim, int kbase, int q) {
    short8 r;
    #pragma unroll
    for (int j = 0; j < 8; ++j) {
        int k = kbase + q * 8 + j;
        float v = (k < klim) ? W[n * ld + k] : 0.f;
        r[j] = (short)bfbits(v);
    }
    return r;
}

__device__ __forceinline__ f32x4 relub(f32x4 v, float b) {
    f32x4 r;
    #pragma unroll
    for (int i = 0; i < 4; ++i) r[i] = fmaxf(v[i] + b, 0.f);
    return r;
}

// sum across the 16 lanes of a quad (xor 1,2,4,8), per component
__device__ __forceinline__ f32x4 bfly16(f32x4 v) {
    #pragma unroll
    for (int d = 1; d <= 8; d <<= 1) {
        #pragma unroll
        for (int i = 0; i < 4; ++i) v[i] += __shfl_xor(v[i], d, 64);
    }
    return v;
}

// per-component softmax over 4 vectors (in place -> weights)
__device__ __forceinline__ void softmax4(f32x4& a, f32x4& b, f32x4& c, f32x4& d) {
    #pragma unroll
    for (int i = 0; i < 4; ++i) {
        float m  = fmaxf(fmaxf(a[i], b[i]), fmaxf(c[i], d[i]));
        float e0 = __expf(a[i] - m), e1 = __expf(b[i] - m);
        float e2 = __expf(c[i] - m), e3 = __expf(d[i] - m);
        float inv = 1.f / (e0 + e1 + e2 + e3);
        a[i] = e0 * inv; b[i] = e1 * inv; c[i] = e2 * inv; d[i] = e3 * inv;
    }
}

// dynamic component extract without scratch (cndmask tree)
__device__ __forceinline__ float sel4(f32x4 v, int r) {
    float a = (r & 1) ? v[1] : v[0];
    float b = (r & 1) ? v[3] : v[2];
    return (r & 2) ? b : a;
}

// per-wave LDS region offsets (bytes); FEATA is unioned with XA+FCA (disjoint lifetimes)
#define FEATA 0        // 4s x 8c x 16row x 16B = 8192
#define XA    0        // 8c x 16row x 16B = 2048   (x activations, written stage12)
#define FCA   2048     // 4c x 16row x 16B = 1024   (im_feat,     written stage7)
#define VIFA  8192     // 4c x 16row x 16B = 1024   (c0=vox, c1/c2=fc out, c3=zeros)
#define RS    9216     // 3c x 64row x 16B = 3072   (raw img rows, bf16)
#define RSZ   12288    // 16B zeros
#define RGB   12304    // 64row x 16B = 1024        (rgb fp32)
#define WLDS  13328

__global__ __launch_bounds__(256) void nerf_mfma(
    const float* __restrict__ vox, const float* __restrict__ img,
    const float* __restrict__ view_w, const float* __restrict__ view_b,
    const float* __restrict__ glob_w, const float* __restrict__ glob_b,
    const float* __restrict__ aggw_w, const float* __restrict__ aggw_b,
    const float* __restrict__ fc_w,   const float* __restrict__ fc_b,
    const float* __restrict__ lr0_w,  const float* __restrict__ lr0_b,
    const float* __restrict__ sgm_w,  const float* __restrict__ sgm_b,
    const float* __restrict__ col1_w, const float* __restrict__ col1_b,
    const float* __restrict__ col2_w, const float* __restrict__ col2_b,
    float* __restrict__ out)
{
    __shared__ int4v smem[(4 * WLDS) / 16];
    const int tid  = threadIdx.x;
    const int wv   = tid >> 6;
    const int lane = tid & 63;
    const int lp   = lane & 15;   // A-row point / C-column
    const int q    = lane >> 4;   // quad (= sample index in row-stages)
    char* S = (char*)smem + wv * WLDS;

    // ---- one-time zero pads ----
    int4v zeroi = {0, 0, 0, 0};
    if (q == 3) {
        *(int4v*)(S + VIFA + (3 * 16 + lp) * 16) = zeroi;   // vif pad chunk (k=24..31)
        if (lp == 0) *(int4v*)(S + RSZ) = zeroi;            // col1 k=112..127 pad
    }
    WFENCE();

    // ---- one-time B-fragments (weights live in VGPRs for the whole kernel) ----
    short8 bg[2][2], blr[4], bc[4][4], bfc;
    #pragma unroll
    for (int nt = 0; nt < 2; ++nt)
        #pragma unroll
        for (int ks = 0; ks < 2; ++ks)
            bg[nt][ks] = ldfrag(glob_w, nt * 16 + lp, 57, 57, ks * 32, q);
    bfc = ldfrag(fc_w, lp, 32, 32, 0, q);
    #pragma unroll
    for (int nt = 0; nt < 4; ++nt) blr[nt] = ldfrag(lr0_w, nt * 16 + lp, 24, 24, 0, q);
    #pragma unroll
    for (int nt = 0; nt < 4; ++nt)
        #pragma unroll
        for (int ks = 0; ks < 4; ++ks)
            bc[nt][ks] = ldfrag(col1_w, nt * 16 + lp, 111, 111, ks * 32, q);

    // ---- per-lane (column-indexed) biases/row-vectors ----
    const float gb0 = glob_b[lp], gb1 = glob_b[16 + lp];
    const float aw0 = aggw_w[lp], aw1 = aggw_w[16 + lp];
    const float fcb = fc_b[lp];
    float lb[4], sw[4], c1b[4], c2w[4];
    #pragma unroll
    for (int nt = 0; nt < 4; ++nt) {
        lb[nt]  = lr0_b[nt * 16 + lp];
        sw[nt]  = sgm_w[nt * 16 + lp];
        c1b[nt] = col1_b[nt * 16 + lp];
        c2w[nt] = col2_w[nt * 16 + lp];
    }
    const float ab0 = aggw_b[0], sb0 = sgm_b[0], c2b0 = col2_b[0];

    #pragma unroll 1
    for (int g = 0; g < GROUPS; ++g) {
        const int n0 = blockIdx.x * (64 * GROUPS) + g * 64 + wv * 16;

        // ---------- stage 1: load row (point lp, sample q); stash rs/rgb/vox ----------
        float raw[23];
        {
            const float* rp = img + ((size_t)(n0 + lp) * 4 + q) * 23;
            #pragma unroll
            for (int i = 0; i < 23; ++i) raw[i] = rp[i];
            int4v w0v = { pk2(raw[0], raw[1]),  pk2(raw[2], raw[3]),
                          pk2(raw[4], raw[5]),  pk2(raw[6], raw[7]) };
            *(int4v*)(S + RS + (q * 16 + lp) * 16) = w0v;
            int4v w1v = { pk2(raw[8], raw[9]),  pk2(raw[10], raw[11]),
                          pk2(raw[12], raw[13]), pk2(raw[14], raw[15]) };
            *(int4v*)(S + RS + (64 + q * 16 + lp) * 16) = w1v;
            int4v w2v = { pk2(raw[16], raw[17]), pk2(raw[18], raw[19]),
                          pk2(raw[20], raw[21]), pk2(raw[22], 0.f) };
            *(int4v*)(S + RS + (128 + q * 16 + lp) * 16) = w2v;
            f32x4 rgbv = { raw[16], raw[17], raw[18], 0.f };
            *(f32x4*)(S + RGB + (q * 16 + lp) * 16) = rgbv;
            if (q == 0) {   // vox -> vif chunk 0
                const float* vp = vox + (size_t)(n0 + lp) * 8;
                f32x4 v0 = *(const f32x4*)vp;
                f32x4 v1 = *(const f32x4*)(vp + 4);
                int4v c8 = { pk2(v0[0], v0[1]), pk2(v0[2], v0[3]),
                             pk2(v1[0], v1[1]), pk2(v1[2], v1[3]) };
                *(int4v*)(S + VIFA + lp * 16) = c8;
            }
        }

        // ---------- stage 2+3: view head, mean/var over samples (shfl over q-bits) ----------
        float feat[64];
        {
            const float d0 = raw[19], d1 = raw[20], d2 = raw[21], d3 = raw[22];
            #pragma unroll
            for (int c = 0; c < 19; ++c) {
                float vf = view_b[c];
                vf = fmaf(d0, view_w[4 * c + 0], vf);
                vf = fmaf(d1, view_w[4 * c + 1], vf);
                vf = fmaf(d2, view_w[4 * c + 2], vf);
                vf = fmaf(d3, view_w[4 * c + 3], vf);
                float v  = raw[c] + fmaxf(vf, 0.f);
                float t  = v + __shfl_xor(v, 16, 64);
                float s4 = t + __shfl_xor(t, 32, 64);
                float m  = s4 * 0.25f;
                float dd = v - m;
                float ds = dd * dd;
                float t2 = ds + __shfl_xor(ds, 16, 64);
                float sq = t2 + __shfl_xor(t2, 32, 64);
                feat[c]      = v;
                feat[19 + c] = sq * (1.f / 3.f);   // unbiased var (ddof=1)
                feat[38 + c] = m;
            }
            #pragma unroll
            for (int c = 57; c < 64; ++c) feat[c] = 0.f;
        }

        // ---------- stage 4: write glob A-fragments ----------
        #pragma unroll
        for (int c = 0; c < 8; ++c) {
            int4v wv4 = { pk2(feat[8 * c + 0], feat[8 * c + 1]), pk2(feat[8 * c + 2], feat[8 * c + 3]),
                          pk2(feat[8 * c + 4], feat[8 * c + 5]), pk2(feat[8 * c + 6], feat[8 * c + 7]) };
            *(int4v*)(S + FEATA + ((q * 8 + c) * 16 + lp) * 16) = wv4;
        }
        WFENCE();

        // ---------- stage 5: glob GEMM (rows=(pt,s), cols=32, K=64) ----------
        f32x4 ag[4][2] = {};
        #pragma unroll
        for (int s = 0; s < 4; ++s)
            #pragma unroll
            for (int ks = 0; ks < 2; ++ks) {
                int4v av = *(int4v*)(S + FEATA + ((s * 8 + ks * 4 + q) * 16 + lp) * 16);
                short8 a = __builtin_bit_cast(short8, av);
                ag[s][0] = MFMA16(a, bg[0][ks], ag[s][0]);
                ag[s][1] = MFMA16(a, bg[1][ks], ag[s][1]);
            }

        // ---------- stage 6: relu+agg softmax -> im_feat (C-layout lanes) ----------
        f32x4 gg[4][2], wsm[4];
        #pragma unroll
        for (int s = 0; s < 4; ++s) {
            gg[s][0] = relub(ag[s][0], gb0);
            gg[s][1] = relub(ag[s][1], gb1);
            f32x4 zp = gg[s][0] * aw0 + gg[s][1] * aw1;
            zp = bfly16(zp);
            wsm[s] = relub(zp, ab0);
        }
        softmax4(wsm[0], wsm[1], wsm[2], wsm[3]);
        f32x4 im0 = {}, im1 = {};
        #pragma unroll
        for (int s = 0; s < 4; ++s) { im0 += gg[s][0] * wsm[s]; im1 += gg[s][1] * wsm[s]; }

        // ---------- stage 7: scatter im_feat to fc A-fragments (bf16) ----------
        {
            short* fca = (short*)(S + FCA);
            #pragma unroll
            for (int r = 0; r < 4; ++r) {
                fca[((lp >> 3)) * 128     + (q * 4 + r) * 8 + (lp & 7)] = (short)bfbits(im0[r]);
                fca[(2 + (lp >> 3)) * 128 + (q * 4 + r) * 8 + (lp & 7)] = (short)bfbits(im1[r]);
            }
        }
        WFENCE();

        // ---------- stage 8: fc GEMM (rows=pts, cols=16, K=32) ----------
        f32x4 fco;
        {
            int4v av = *(int4v*)(S + FCA + (q * 16 + lp) * 16);
            f32x4 acc = {};
            acc = MFMA16(__builtin_bit_cast(short8, av), bfc, acc);
            fco = relub(acc, fcb);
        }

        // ---------- stage 9: fc out -> vif chunks 1,2 ----------
        {
            short* vfa = (short*)(S + VIFA);
            #pragma unroll
            for (int r = 0; r < 4; ++r)
                vfa[(1 + (lp >> 3)) * 128 + (q * 4 + r) * 8 + (lp & 7)] = (short)bfbits(fco[r]);
        }
        WFENCE();

        // ---------- stage 10: lr0 GEMM (rows=pts, cols=64, K=32) ----------
        f32x4 x4[4];
        {
            int4v av = *(int4v*)(S + VIFA + (q * 16 + lp) * 16);
            short8 a = __builtin_bit_cast(short8, av);
            #pragma unroll
            for (int nt = 0; nt < 4; ++nt) {
                f32x4 acc = {};
                acc = MFMA16(a, blr[nt], acc);
                x4[nt] = relub(acc, lb[nt]);
            }
        }

        // ---------- stage 11: sigma = softplus(sgm_w . x) ----------
        f32x4 sig;
        {
            f32x4 sp = x4[0] * sw[0] + x4[1] * sw[1] + x4[2] * sw[2] + x4[3] * sw[3];
            sp = bfly16(sp);
            #pragma unroll
            for (int i = 0; i < 4; ++i) {
                float z = sp[i] + sb0;
                sig[i] = fmaxf(z, 0.f) + log1pf(__expf(-fabsf(z)));
            }
        }

        // ---------- stage 12: x -> col1 A-fragments (chunks 0..7) ----------
        {
            short* xa = (short*)(S + XA);
            #pragma unroll
            for (int nt = 0; nt < 4; ++nt)
                #pragma unroll
                for (int r = 0; r < 4; ++r)
                    xa[(nt * 2 + (lp >> 3)) * 128 + (q * 4 + r) * 8 + (lp & 7)] =
                        (short)bfbits(x4[nt][r]);
        }
        WFENCE();

        // ---------- stage 13: col1 GEMM (rows=(pt,s), cols=64, K=128) ----------
        f32x4 ac[4][4] = {};
        {
            short8 ax0 = __builtin_bit_cast(short8, *(int4v*)(S + XA + (q * 16 + lp) * 16));
            short8 ax1 = __builtin_bit_cast(short8, *(int4v*)(S + XA + ((4 + q) * 16 + lp) * 16));
            #pragma unroll
            for (int mt = 0; mt < 4; ++mt) {
                const char* a2p = (q < 3) ? (S + VIFA + (q * 16 + lp) * 16)
                                          : (S + RS + (mt * 16 + lp) * 16);
                const char* a3p = (q == 0) ? (S + RS + (64 + mt * 16 + lp) * 16)
                                : (q == 1) ? (S + RS + (128 + mt * 16 + lp) * 16)
                                           : (S + RSZ);
                short8 a2 = __builtin_bit_cast(short8, *(const int4v*)a2p);
                short8 a3 = __builtin_bit_cast(short8, *(const int4v*)a3p);
                #pragma unroll
                for (int nt = 0; nt < 4; ++nt) {
                    ac[mt][nt] = MFMA16(ax0, bc[nt][0], ac[mt][nt]);
                    ac[mt][nt] = MFMA16(ax1, bc[nt][1], ac[mt][nt]);
                    ac[mt][nt] = MFMA16(a2,  bc[nt][2], ac[mt][nt]);
                    ac[mt][nt] = MFMA16(a3,  bc[nt][3], ac[mt][nt]);
                }
            }
        }

        // ---------- stage 14: col2, softmax over s, color + store ----------
        f32x4 z2[4];
        #pragma unroll
        for (int s = 0; s < 4; ++s) {
            f32x4 zp = {};
            #pragma unroll
            for (int nt = 0; nt < 4; ++nt) {
                f32x4 h = relub(ac[s][nt], c1b[nt]);
                zp += h * c2w[nt];
            }
            zp = bfly16(zp);
            z2[s] = relub(zp, c2b0);
        }
        softmax4(z2[0], z2[1], z2[2], z2[3]);
        if (lp < 4) {
            float cr = 0.f, cg = 0.f, cb = 0.f;
            #pragma unroll
            for (int s = 0; s < 4; ++s) {
                f32x4 rgbv = *(f32x4*)(S + RGB + (s * 16 + q * 4 + lp) * 16);
                float ws = sel4(z2[s], lp);
                cr = fmaf(rgbv[0], ws, cr);
                cg = fmaf(rgbv[1], ws, cg);
                cb = fmaf(rgbv[2], ws, cb);
            }
            f32x4 o = { cr, cg, cb, sel4(sig, lp) };
            *(f32x4*)(out + (size_t)(n0 + q * 4 + lp) * 4) = o;
        }
        WFENCE();
    }
}

extern "C" void kernel_launch(void* const* d_in, const int* in_sizes, int n_in,
                              void* d_out, int out_size, void* d_ws, size_t ws_size,
                              hipStream_t stream) {
    (void)in_sizes; (void)n_in; (void)out_size; (void)d_ws; (void)ws_size;
    nerf_mfma<<<dim3(NPTS / (64 * GROUPS)), dim3(256), 0, stream>>>(
        (const float*)d_in[0],  (const float*)d_in[1],
        (const float*)d_in[2],  (const float*)d_in[3],
        (const float*)d_in[4],  (const float*)d_in[5],
        (const float*)d_in[6],  (const float*)d_in[7],
        (const float*)d_in[8],  (const float*)d_in[9],
        (const float*)d_in[10], (const float*)d_in[11],
        (const float*)d_in[12], (const float*)d_in[13],
        (const float*)d_in[14], (const float*)d_in[15],
        (const float*)d_in[16], (const float*)d_in[17],
        (float*)d_out);
}

// Round 4
// 504.150 us; speedup vs baseline: 3.4291x; 1.1337x over previous
//
#include <hip/hip_runtime.h>
#include <math.h>

#define NPTS   524288
#define GROUPS 4          // 16 pts/wave/group * 4 waves * 4 groups = 256 pts/block

typedef __attribute__((ext_vector_type(8))) short  short8;
typedef __attribute__((ext_vector_type(4))) float  f32x4;
typedef __attribute__((ext_vector_type(4))) int    int4v;

#define MFMA16(a, b, c) __builtin_amdgcn_mfma_f32_16x16x32_bf16((a), (b), (c), 0, 0, 0)
#define SB8(x) __builtin_bit_cast(short8, (x))

// wave-private LDS ordering: compile-time fence only (LDS executes in wave
// program order; block barrier not needed since LDS stripes are per-wave)
#define WFENCE() __builtin_amdgcn_wave_barrier()

// f32 -> bf16 bits, round-half-up
__device__ __forceinline__ unsigned bfbits(float x) {
    union { float f; unsigned u; } a; a.f = x;
    return (a.u + 0x8000u) >> 16;
}
#if __has_builtin(__builtin_amdgcn_cvt_pk_bf16_f32)
__device__ __forceinline__ int pk2(float lo, float hi) {
    return __builtin_bit_cast(int, __builtin_amdgcn_cvt_pk_bf16_f32(lo, hi));
}
#else
__device__ __forceinline__ int pk2(float lo, float hi) {
    union { float f; unsigned u; } a, b; a.f = lo; b.f = hi;
    return (int)(((a.u + 0x8000u) >> 16) | ((b.u + 0x8000u) & 0xFFFF0000u));
}
#endif

__device__ __forceinline__ f32x4 relub(f32x4 v, float b) {
    f32x4 r;
    #pragma unroll
    for (int i = 0; i < 4; ++i) r[i] = fmaxf(v[i] + b, 0.f);
    return r;
}

// sum across the 16 lanes of a quad (xor 1,2,4,8), per component
__device__ __forceinline__ f32x4 bfly16(f32x4 v) {
    #pragma unroll
    for (int d = 1; d <= 8; d <<= 1) {
        #pragma unroll
        for (int i = 0; i < 4; ++i) v[i] += __shfl_xor(v[i], d, 64);
    }
    return v;
}

// per-component softmax over 4 vectors (in place -> weights)
__device__ __forceinline__ void softmax4(f32x4& a, f32x4& b, f32x4& c, f32x4& d) {
    #pragma unroll
    for (int i = 0; i < 4; ++i) {
        float m  = fmaxf(fmaxf(a[i], b[i]), fmaxf(c[i], d[i]));
        float e0 = __expf(a[i] - m), e1 = __expf(b[i] - m);
        float e2 = __expf(c[i] - m), e3 = __expf(d[i] - m);
        float inv = 1.f / (e0 + e1 + e2 + e3);
        a[i] = e0 * inv; b[i] = e1 * inv; c[i] = e2 * inv; d[i] = e3 * inv;
    }
}

// dynamic component extract without scratch (cndmask tree)
__device__ __forceinline__ float sel4(f32x4 v, int r) {
    float a = (r & 1) ? v[1] : v[0];
    float b = (r & 1) ? v[3] : v[2];
    return (r & 2) ? b : a;
}

// ---------------- weight pre-pack kernel: 25 fragments x 64 lanes ----------------
// ws fragment index: bg(nt,ks)=nt*2+ks (0..3), bfc=4, blr(nt)=5+nt, bc(nt,ks)=9+nt*4+ks
__global__ __launch_bounds__(64) void pack_weights(
    const float* __restrict__ glob_w, const float* __restrict__ fc_w,
    const float* __restrict__ lr0_w,  const float* __restrict__ col1_w,
    int4v* __restrict__ ws)
{
    const int f = blockIdx.x;
    const int l = threadIdx.x;
    const int q = l >> 4, lp = l & 15;
    const float* W; int n, ld, klim, kbase;
    if (f < 4)       { W = glob_w; n = (f >> 1) * 16 + lp; ld = 57;  klim = 57;  kbase = (f & 1) * 32; }
    else if (f == 4) { W = fc_w;   n = lp;                 ld = 32;  klim = 32;  kbase = 0; }
    else if (f < 9)  { W = lr0_w;  n = (f - 5) * 16 + lp;  ld = 24;  klim = 24;  kbase = 0; }
    else             { W = col1_w; n = ((f - 9) >> 2) * 16 + lp; ld = 111; klim = 111; kbase = ((f - 9) & 3) * 32; }
    short8 r;
    #pragma unroll
    for (int j = 0; j < 8; ++j) {
        int k = kbase + q * 8 + j;
        float v = (k < klim) ? W[n * ld + k] : 0.f;
        r[j] = (short)bfbits(v);
    }
    ws[f * 64 + l] = __builtin_bit_cast(int4v, r);
}

// per-wave LDS region offsets (bytes)
#define FEATA 0        // two-pass staging: 4s x 4cc x 16row x 16B = 4096
#define XA    0        // 8c x 16row x 16B = 2048   (x activations; FEATA union)
#define FCA   2048     // 4c x 16row x 16B = 1024   (im_feat; FEATA union)
#define VIFA  4096     // 4c x 16row x 16B = 1024   (c0=vox, c1/c2=fc out, c3=zeros persistent)
#define RS    5120     // 3c x 64row x 16B = 3072   (raw img rows, bf16)
#define RGB   8192     // 64row x 16B = 1024        (rgb fp32)
#define WLDS  9216

__global__ __launch_bounds__(256) void nerf_mfma(
    const float* __restrict__ vox, const float* __restrict__ img,
    const float* __restrict__ view_w, const float* __restrict__ view_b,
    const float* __restrict__ glob_b,
    const float* __restrict__ aggw_w, const float* __restrict__ aggw_b,
    const float* __restrict__ fc_b,
    const float* __restrict__ lr0_b,
    const float* __restrict__ sgm_w,  const float* __restrict__ sgm_b,
    const float* __restrict__ col1_b,
    const float* __restrict__ col2_w, const float* __restrict__ col2_b,
    const int4v* __restrict__ wsv,
    float* __restrict__ out)
{
    __shared__ int4v smem[(4 * WLDS) / 16];
    const int tid  = threadIdx.x;
    const int wv   = tid >> 6;
    const int lane = tid & 63;
    const int lp   = lane & 15;   // A-row point / C-column
    const int q    = lane >> 4;   // quad (= sample index in row-stages)
    char* S = (char*)smem + wv * WLDS;

    // ---- one-time zero pad: VIFA chunk 3 (vif k=24..31; also col1 k96..127 zeros) ----
    int4v zeroi = {0, 0, 0, 0};
    if (q == 3) *(int4v*)(S + VIFA + (3 * 16 + lp) * 16) = zeroi;
    WFENCE();

    // ---- per-lane (column-indexed) biases/row-vectors ----
    const float gb0 = glob_b[lp], gb1 = glob_b[16 + lp];
    const float aw0 = aggw_w[lp], aw1 = aggw_w[16 + lp];
    const float fcb = fc_b[lp];
    float lb[4], sw[4], c1b[4], c2w[4];
    #pragma unroll
    for (int nt = 0; nt < 4; ++nt) {
        lb[nt]  = lr0_b[nt * 16 + lp];
        sw[nt]  = sgm_w[nt * 16 + lp];
        c1b[nt] = col1_b[nt * 16 + lp];
        c2w[nt] = col2_w[nt * 16 + lp];
    }
    const float ab0 = aggw_b[0], sb0 = sgm_b[0], c2b0 = col2_b[0];

    #pragma unroll 1
    for (int g = 0; g < GROUPS; ++g) {
        const int n0 = blockIdx.x * (64 * GROUPS) + g * 64 + wv * 16;

        // ---------- stage 1: load row (point lp, sample q); stash rs/rgb/vox ----------
        float raw[23];
        {
            const float* rp = img + ((size_t)(n0 + lp) * 4 + q) * 23;
            #pragma unroll
            for (int i = 0; i < 23; ++i) raw[i] = rp[i];
            int4v w0v = { pk2(raw[0], raw[1]),   pk2(raw[2], raw[3]),
                          pk2(raw[4], raw[5]),   pk2(raw[6], raw[7]) };
            *(int4v*)(S + RS + (q * 16 + lp) * 16) = w0v;
            int4v w1v = { pk2(raw[8], raw[9]),   pk2(raw[10], raw[11]),
                          pk2(raw[12], raw[13]), pk2(raw[14], raw[15]) };
            *(int4v*)(S + RS + (64 + q * 16 + lp) * 16) = w1v;
            int4v w2v = { pk2(raw[16], raw[17]), pk2(raw[18], raw[19]),
                          pk2(raw[20], raw[21]), pk2(raw[22], 0.f) };
            *(int4v*)(S + RS + (128 + q * 16 + lp) * 16) = w2v;
            f32x4 rgbv = { raw[16], raw[17], raw[18], 0.f };
            *(f32x4*)(S + RGB + (q * 16 + lp) * 16) = rgbv;
            if (q == 0) {   // vox -> vif chunk 0
                const float* vp = vox + (size_t)(n0 + lp) * 8;
                f32x4 v0 = *(const f32x4*)vp;
                f32x4 v1 = *(const f32x4*)(vp + 4);
                int4v c8 = { pk2(v0[0], v0[1]), pk2(v0[2], v0[3]),
                             pk2(v1[0], v1[1]), pk2(v1[2], v1[3]) };
                *(int4v*)(S + VIFA + lp * 16) = c8;
            }
        }

        // ---------- stage 2+3: view head, mean/var, pack feat into 32 dwords ----------
        unsigned pkf[32];
        {
            #pragma unroll
            for (int i = 0; i < 32; ++i) pkf[i] = 0;
            const float d0 = raw[19], d1 = raw[20], d2 = raw[21], d3 = raw[22];
            #pragma unroll
            for (int c = 0; c < 19; ++c) {
                float vf = view_b[c];
                vf = fmaf(d0, view_w[4 * c + 0], vf);
                vf = fmaf(d1, view_w[4 * c + 1], vf);
                vf = fmaf(d2, view_w[4 * c + 2], vf);
                vf = fmaf(d3, view_w[4 * c + 3], vf);
                float v  = raw[c] + fmaxf(vf, 0.f);
                float t  = v + __shfl_xor(v, 16, 64);
                float s4 = t + __shfl_xor(t, 32, 64);
                float m  = s4 * 0.25f;
                float dd = v - m;
                float ds = dd * dd;
                float t2 = ds + __shfl_xor(ds, 16, 64);
                float sq = t2 + __shfl_xor(t2, 32, 64);
                float vr = sq * (1.f / 3.f);   // unbiased var (ddof=1)
                pkf[c >> 1]        |= bfbits(v)  << ((c & 1) * 16);
                pkf[(19 + c) >> 1] |= bfbits(vr) << (((19 + c) & 1) * 16);
                pkf[(38 + c) >> 1] |= bfbits(m)  << (((38 + c) & 1) * 16);
            }
        }

        // ---------- stage 4+5: glob GEMM, two K-passes through 4KB FEATA ----------
        f32x4 ag[4][2] = {};
        #pragma unroll
        for (int pass = 0; pass < 2; ++pass) {
            #pragma unroll
            for (int cc = 0; cc < 4; ++cc) {
                const int base = (pass * 4 + cc) * 4;
                int4v wv4 = { (int)pkf[base], (int)pkf[base + 1],
                              (int)pkf[base + 2], (int)pkf[base + 3] };
                *(int4v*)(S + FEATA + ((q * 4 + cc) * 16 + lp) * 16) = wv4;
            }
            WFENCE();
            int4v bg0 = wsv[(0 + pass) * 64 + lane];   // glob nt=0, ks=pass
            int4v bg1 = wsv[(2 + pass) * 64 + lane];   // glob nt=1, ks=pass
            #pragma unroll
            for (int s = 0; s < 4; ++s) {
                int4v av = *(int4v*)(S + FEATA + ((s * 4 + q) * 16 + lp) * 16);
                ag[s][0] = MFMA16(SB8(av), SB8(bg0), ag[s][0]);
                ag[s][1] = MFMA16(SB8(av), SB8(bg1), ag[s][1]);
            }
            WFENCE();
        }

        // ---------- stage 6: relu+agg softmax -> im_feat (C-layout lanes) ----------
        f32x4 gg[4][2], wsm[4];
        #pragma unroll
        for (int s = 0; s < 4; ++s) {
            gg[s][0] = relub(ag[s][0], gb0);
            gg[s][1] = relub(ag[s][1], gb1);
            f32x4 zp = gg[s][0] * aw0 + gg[s][1] * aw1;
            zp = bfly16(zp);
            wsm[s] = relub(zp, ab0);
        }
        softmax4(wsm[0], wsm[1], wsm[2], wsm[3]);
        f32x4 im0 = {}, im1 = {};
        #pragma unroll
        for (int s = 0; s < 4; ++s) { im0 += gg[s][0] * wsm[s]; im1 += gg[s][1] * wsm[s]; }

        // ---------- stage 7: scatter im_feat to fc A-fragments (bf16) ----------
        {
            short* fca = (short*)(S + FCA);
            #pragma unroll
            for (int r = 0; r < 4; ++r) {
                fca[((lp >> 3)) * 128     + (q * 4 + r) * 8 + (lp & 7)] = (short)bfbits(im0[r]);
                fca[(2 + (lp >> 3)) * 128 + (q * 4 + r) * 8 + (lp & 7)] = (short)bfbits(im1[r]);
            }
        }
        WFENCE();

        // ---------- stage 8: fc GEMM (rows=pts, cols=16, K=32) ----------
        f32x4 fco;
        {
            int4v av = *(int4v*)(S + FCA + (q * 16 + lp) * 16);
            int4v bfc = wsv[4 * 64 + lane];
            f32x4 acc = {};
            acc = MFMA16(SB8(av), SB8(bfc), acc);
            fco = relub(acc, fcb);
        }

        // ---------- stage 9: fc out -> vif chunks 1,2 ----------
        {
            short* vfa = (short*)(S + VIFA);
            #pragma unroll
            for (int r = 0; r < 4; ++r)
                vfa[(1 + (lp >> 3)) * 128 + (q * 4 + r) * 8 + (lp & 7)] = (short)bfbits(fco[r]);
        }
        WFENCE();

        // ---------- stage 10: lr0 GEMM (rows=pts, cols=64, K=32) ----------
        f32x4 x4[4];
        {
            int4v av = *(int4v*)(S + VIFA + (q * 16 + lp) * 16);
            #pragma unroll
            for (int nt = 0; nt < 4; ++nt) {
                int4v blr = wsv[(5 + nt) * 64 + lane];
                f32x4 acc = {};
                acc = MFMA16(SB8(av), SB8(blr), acc);
                x4[nt] = relub(acc, lb[nt]);
            }
        }

        // ---------- stage 11: sigma = softplus(sgm_w . x) ----------
        f32x4 sig;
        {
            f32x4 sp = x4[0] * sw[0] + x4[1] * sw[1] + x4[2] * sw[2] + x4[3] * sw[3];
            sp = bfly16(sp);
            #pragma unroll
            for (int i = 0; i < 4; ++i) {
                float z = sp[i] + sb0;
                sig[i] = fmaxf(z, 0.f) + log1pf(__expf(-fabsf(z)));
            }
        }

        // ---------- stage 12: x -> col1 A-fragments (chunks 0..7) ----------
        {
            short* xa = (short*)(S + XA);
            #pragma unroll
            for (int nt = 0; nt < 4; ++nt)
                #pragma unroll
                for (int r = 0; r < 4; ++r)
                    xa[(nt * 2 + (lp >> 3)) * 128 + (q * 4 + r) * 8 + (lp & 7)] =
                        (short)bfbits(x4[nt][r]);
        }
        WFENCE();

        // ---------- stage 13: col1 GEMM, nt-tiled with immediate col2 reduction ----------
        f32x4 zp[4] = {};
        {
            int4v ax0 = *(int4v*)(S + XA + (q * 16 + lp) * 16);
            int4v ax1 = *(int4v*)(S + XA + ((4 + q) * 16 + lp) * 16);
            int4v a2v[4], a3v[4];
            #pragma unroll
            for (int mt = 0; mt < 4; ++mt) {
                const char* a2p = (q < 3) ? (S + VIFA + (q * 16 + lp) * 16)
                                          : (S + RS + (mt * 16 + lp) * 16);
                const char* a3p = (q == 0) ? (S + RS + (64 + mt * 16 + lp) * 16)
                                : (q == 1) ? (S + RS + (128 + mt * 16 + lp) * 16)
                                           : (S + VIFA + (3 * 16 + lp) * 16);  // zeros
                a2v[mt] = *(const int4v*)a2p;
                a3v[mt] = *(const int4v*)a3p;
            }
            #pragma unroll
            for (int nt = 0; nt < 4; ++nt) {
                int4v b0 = wsv[(9 + nt * 4 + 0) * 64 + lane];
                int4v b1 = wsv[(9 + nt * 4 + 1) * 64 + lane];
                int4v b2 = wsv[(9 + nt * 4 + 2) * 64 + lane];
                int4v b3 = wsv[(9 + nt * 4 + 3) * 64 + lane];
                #pragma unroll
                for (int mt = 0; mt < 4; ++mt) {
                    f32x4 acc = {};
                    acc = MFMA16(SB8(ax0),      SB8(b0), acc);
                    acc = MFMA16(SB8(ax1),      SB8(b1), acc);
                    acc = MFMA16(SB8(a2v[mt]),  SB8(b2), acc);
                    acc = MFMA16(SB8(a3v[mt]),  SB8(b3), acc);
                    f32x4 h = relub(acc, c1b[nt]);
                    zp[mt] += h * c2w[nt];
                }
            }
        }

        // ---------- stage 14: softmax over s, color + store ----------
        f32x4 z2[4];
        #pragma unroll
        for (int s = 0; s < 4; ++s) z2[s] = relub(bfly16(zp[s]), c2b0);
        softmax4(z2[0], z2[1], z2[2], z2[3]);
        if (lp < 4) {
            float cr = 0.f, cg = 0.f, cb = 0.f;
            #pragma unroll
            for (int s = 0; s < 4; ++s) {
                f32x4 rgbv = *(f32x4*)(S + RGB + (s * 16 + q * 4 + lp) * 16);
                float ws = sel4(z2[s], lp);
                cr = fmaf(rgbv[0], ws, cr);
                cg = fmaf(rgbv[1], ws, cg);
                cb = fmaf(rgbv[2], ws, cb);
            }
            f32x4 o = { cr, cg, cb, sel4(sig, lp) };
            *(f32x4*)(out + (size_t)(n0 + q * 4 + lp) * 4) = o;
        }
        WFENCE();
    }
}

extern "C" void kernel_launch(void* const* d_in, const int* in_sizes, int n_in,
                              void* d_out, int out_size, void* d_ws, size_t ws_size,
                              hipStream_t stream) {
    (void)in_sizes; (void)n_in; (void)out_size; (void)ws_size;
    pack_weights<<<dim3(25), dim3(64), 0, stream>>>(
        (const float*)d_in[4],   // glob_w
        (const float*)d_in[8],   // fc_w
        (const float*)d_in[10],  // lr0_w
        (const float*)d_in[14],  // col1_w
        (int4v*)d_ws);
    nerf_mfma<<<dim3(NPTS / (64 * GROUPS)), dim3(256), 0, stream>>>(
        (const float*)d_in[0],  (const float*)d_in[1],
        (const float*)d_in[2],  (const float*)d_in[3],
        (const float*)d_in[5],
        (const float*)d_in[6],  (const float*)d_in[7],
        (const float*)d_in[9],
        (const float*)d_in[11],
        (const float*)d_in[12], (const float*)d_in[13],
        (const float*)d_in[15],
        (const float*)d_in[16], (const float*)d_in[17],
        (const int4v*)d_ws,
        (float*)d_out);
}